// Round 5
// baseline (454.281 us; speedup 1.0000x reference)
//
#include <hip/hip_runtime.h>

#define S_LEN 512
#define BATCH 256
#define L 128
#define PAD_ID 0
#define START_ID 1

typedef short short8 __attribute__((ext_vector_type(8)));
typedef float  f32x4 __attribute__((ext_vector_type(4)));
typedef unsigned short u16x2 __attribute__((ext_vector_type(2)));
typedef unsigned int   u32x4 __attribute__((ext_vector_type(4)));

__device__ __forceinline__ unsigned int umax2(unsigned int a, unsigned int b) {
    u16x2 x = __builtin_bit_cast(u16x2, a), y = __builtin_bit_cast(u16x2, b);
#if defined(__has_builtin) && __has_builtin(__builtin_elementwise_max)
    return __builtin_bit_cast(unsigned int, __builtin_elementwise_max(x, y));  // v_pk_max_u16
#else
    u16x2 r; r.x = x.x > y.x ? x.x : y.x; r.y = x.y > y.y ? x.y : y.y;
    return __builtin_bit_cast(unsigned int, r);
#endif
}
__device__ __forceinline__ float frcp(float x) {
#if defined(__has_builtin) && __has_builtin(__builtin_amdgcn_rcpf)
    return __builtin_amdgcn_rcpf(x);
#else
    return 1.0f / x;
#endif
}
__device__ __forceinline__ unsigned short f2bf(float f) {   // RNE, f >= 0 here
    unsigned int u = __builtin_bit_cast(unsigned int, f);
    return (unsigned short)((u + 0x7fffu + ((u >> 16) & 1u)) >> 16);
}
__device__ __forceinline__ float bf2f(unsigned short b) {
    return __builtin_bit_cast(float, (unsigned int)b << 16);
}

// One 64-lane wave per batch row; no __syncthreads anywhere (same-wave DS ordering).
// cur = q(1x128) @ expT(128x128) via 32x mfma_f32_16x16x32_bf16, q replicated
// across all 16 A-rows (4 ds_read_b128/lane), expT resident in 32 B-frags (128 VGPRs).
// Scale: LAG-FREE uniform normalizer msc = max(q_{t-1}[0..7]) via one extra broadcast
// ds_read_b128 + packed-u16 max (bf16>0). No feedback loop -> unconditionally stable;
// spread bound |fs_j - fs_i| <= ~12 per step keeps stored q in e^[-23,+23].
// rcp(msc) is consumed only after the MFMAs -> latency hidden.
__global__ __launch_bounds__(64, 1) void k_scan(
        const float* __restrict__ emit, const int* __restrict__ labels,
        const void* __restrict__ masks, const float* __restrict__ T,
        float* __restrict__ out) {
    const int b = blockIdx.x;
    const int lane = threadIdx.x;            // 0..63
    const int g = lane >> 4, m = lane & 15;  // quad, col
    const int ja = g * 32 + m, jb = ja + 16; // this lane's two output labels

    __shared__ __align__(16) short pb[L];    // q as bf16 bits

    // ---- self-detect mask encoding from first 8KB (uniform across blocks; L2 broadcast).
    // byte-packed prefix-ones rows give words like 0x01010101 (>1, != 1.0f pattern);
    // int32 words are {0,1}; float words are {0, 0x3f800000}.
    const unsigned int* mw0 = (const unsigned int*)masks;
    int pred = 0;
    #pragma unroll
    for (int k = 0; k < 32; ++k) {
        unsigned int w0 = mw0[lane + 64 * k];
        pred |= (w0 > 1u && w0 != 0x3f800000u);
    }
    const bool isbyte = (__ballot(pred) != 0ull);

    // ---- length of row b (mask is prefix-ones) ----
    int len;
    {
        int cnt = 0;
        if (isbyte) {
            const unsigned int* mw = (const unsigned int*)masks + b * (S_LEN / 4);
            #pragma unroll
            for (int k = 0; k < 2; ++k) {
                unsigned int w0 = mw[lane + 64 * k];
                cnt += ((w0 & 0xffu) != 0) + ((w0 & 0xff00u) != 0) +
                       ((w0 & 0xff0000u) != 0) + ((w0 & 0xff000000u) != 0);
            }
        } else {
            const unsigned int* mw = (const unsigned int*)masks + b * S_LEN;
            #pragma unroll
            for (int k = 0; k < 8; ++k) cnt += (mw[lane + 64 * k] != 0u);
        }
        #pragma unroll
        for (int off = 32; off; off >>= 1) cnt += __shfl_xor(cnt, off, 64);
        len = cnt;
    }

    // ---- expT into 32 B-fragments: element rr = expT[k = kt*32 + g*8 + rr][n = nt*16 + m].
    // Same k-mapping is used for A below, so any k-permutation error cancels identically.
    auto ldb = [&](int nt, int kt) -> short8 {
        short8 r;
        #pragma unroll
        for (int rr = 0; rr < 8; ++rr)
            r[rr] = (short)f2bf(__expf(T[(kt * 32 + g * 8 + rr) * L + nt * 16 + m]));
        return r;
    };
    short8 B00=ldb(0,0),B01=ldb(0,1),B02=ldb(0,2),B03=ldb(0,3);
    short8 B10=ldb(1,0),B11=ldb(1,1),B12=ldb(1,2),B13=ldb(1,3);
    short8 B20=ldb(2,0),B21=ldb(2,1),B22=ldb(2,2),B23=ldb(2,3);
    short8 B30=ldb(3,0),B31=ldb(3,1),B32=ldb(3,2),B33=ldb(3,3);
    short8 B40=ldb(4,0),B41=ldb(4,1),B42=ldb(4,2),B43=ldb(4,3);
    short8 B50=ldb(5,0),B51=ldb(5,1),B52=ldb(5,2),B53=ldb(5,3);
    short8 B60=ldb(6,0),B61=ldb(6,1),B62=ldb(6,2),B63=ldb(6,3);
    short8 B70=ldb(7,0),B71=ldb(7,1),B72=ldb(7,2),B73=ldb(7,3);

    // ---- fs0, exact max (prologue shuffles OK), q0 = exp(fs0 - S) ----
    float fa = emit[b * L + ja] + T[START_ID * L + ja];
    float fb = emit[b * L + jb] + T[START_ID * L + jb];
    float mx = fmaxf(fa, fb);
    #pragma unroll
    for (int off = 32; off; off >>= 1) mx = fmaxf(mx, __shfl_xor(mx, off, 64));
    float S = mx;
    pb[ja] = (short)f2bf(__expf(fa - S));
    pb[jb] = (short)f2bf(__expf(fb - S));
    float eTpa = __expf(T[ja * L + PAD_ID]);
    float eTpb = __expf(T[jb * L + PAD_ID]);

    // emit prefetch, 2 steps deep (HBM latency ~900 cyc > 1 step)
    float xa = 0.f, xb = 0.f, la1 = 0.f, lb1 = 0.f;
    if (len > 1) {
        xa = __expf(emit[(1 * BATCH + b) * L + ja]);
        xb = __expf(emit[(1 * BATCH + b) * L + jb]);
    }
    if (len > 2) {
        la1 = emit[(2 * BATCH + b) * L + ja];
        lb1 = emit[(2 * BATCH + b) * L + jb];
    }

    const short8* lds8 = (const short8*)pb;

#define MMACC(C, Bq0, Bq1, Bq2, Bq3) \
    C = __builtin_amdgcn_mfma_f32_16x16x32_bf16(A0, Bq0, C, 0, 0, 0); \
    C = __builtin_amdgcn_mfma_f32_16x16x32_bf16(A1, Bq1, C, 0, 0, 0); \
    C = __builtin_amdgcn_mfma_f32_16x16x32_bf16(A2, Bq2, C, 0, 0, 0); \
    C = __builtin_amdgcn_mfma_f32_16x16x32_bf16(A3, Bq3, C, 0, 0, 0);

    for (int t = 1; t < len; ++t) {
        // A-frags of q_{t-1}: lane reads 16B at kt*64 + g*16 (A rows replicated)
        short8 A0 = lds8[0 + g], A1 = lds8[4 + g], A2 = lds8[8 + g], A3 = lds8[12 + g];
        short8 M8 = lds8[0];                 // uniform broadcast: q_{t-1}[0..7]

        // lag-free uniform scale (bf16>0 -> u16 compare); consumed post-MFMA
        u32x4 mu = __builtin_bit_cast(u32x4, M8);
        unsigned int um = umax2(umax2(mu.x, mu.y), umax2(mu.z, mu.w));
        u16x2 uh = __builtin_bit_cast(u16x2, um);
        float msc = bf2f(uh.x > uh.y ? uh.x : uh.y);
        float kk = frcp(msc);

        f32x4 c0 = {0,0,0,0}, c1 = c0, c2 = c0, c3 = c0, c4 = c0, c5 = c0, c6 = c0, c7 = c0;
        MMACC(c0, B00, B01, B02, B03)
        MMACC(c1, B10, B11, B12, B13)
        MMACC(c2, B20, B21, B22, B23)
        MMACC(c3, B30, B31, B32, B33)
        MMACC(c4, B40, B41, B42, B43)
        MMACC(c5, B50, B51, B52, B53)
        MMACC(c6, B60, B61, B62, B63)
        MMACC(c7, B70, B71, B72, B73)

        // cur for this lane's two labels (all C-rows identical; C col = lane&15 [m89])
        float ca = (g == 0) ? c0[0] : (g == 1) ? c2[0] : (g == 2) ? c4[0] : c6[0];
        float cb = (g == 0) ? c1[0] : (g == 1) ? c3[0] : (g == 2) ? c5[0] : c7[0];

        float pa = ca * kk * xa;
        float pv = cb * kk * xb;
        pb[ja] = (short)f2bf(pa);    // same-wave DS order: next iter's reads see these
        pb[jb] = (short)f2bf(pv);
        S += __logf(msc);

        // rotate emit prefetch
        if (t + 2 < len) {
            float na = emit[((t + 2) * BATCH + b) * L + ja];
            float nb = emit[((t + 2) * BATCH + b) * L + jb];
            xa = __expf(la1); xb = __expf(lb1);
            la1 = na; lb1 = nb;
        } else {
            xa = __expf(la1); xb = __expf(lb1);
        }
    }

    // ---- encode_b = S + log(sum_j q_j * exp(T[j][PAD])) ----
    float qa = bf2f((unsigned short)pb[ja]);
    float qb = bf2f((unsigned short)pb[jb]);
    float ev = qa * eTpa + qb * eTpb;            // lanes cover all 128 j exactly once
    #pragma unroll
    for (int off = 32; off; off >>= 1) ev += __shfl_xor(ev, off, 64);
    float enc = S + __logf(ev);

    // ---- gold_b ----
    float gsum = 0.f;
    for (int t = lane; t < len; t += 64) {
        int nxt = labels[b * S_LEN + t];
        int prv = t ? labels[b * S_LEN + t - 1] : START_ID;
        gsum += emit[(t * BATCH + b) * L + nxt] + T[prv * L + nxt];
        if (t == len - 1) gsum += T[nxt * L + PAD_ID];
    }
    #pragma unroll
    for (int off = 32; off; off >>= 1) gsum += __shfl_xor(gsum, off, 64);

    if (lane == 0) atomicAdd(out, enc - gsum);
}

extern "C" void kernel_launch(void* const* d_in, const int* in_sizes, int n_in,
                              void* d_out, int out_size, void* d_ws, size_t ws_size,
                              hipStream_t stream) {
    const float* emit   = (const float*)d_in[0];
    const int*   labels = (const int*)d_in[1];
    const void*  masks  = d_in[2];
    const float* T      = (const float*)d_in[3];
    float* out = (float*)d_out;

    hipMemsetAsync(d_out, 0, sizeof(float), stream);
    k_scan<<<dim3(BATCH), dim3(64), 0, stream>>>(emit, labels, masks, T, out);
}

// Round 6
// 307.189 us; speedup vs baseline: 1.4788x; 1.4788x over previous
//
#include <hip/hip_runtime.h>

#define S_LEN 512
#define BATCH 256
#define L 128
#define PAD_ID 0
#define START_ID 1

typedef short short8 __attribute__((ext_vector_type(8)));
typedef float  f32x4 __attribute__((ext_vector_type(4)));
typedef unsigned short u16x2 __attribute__((ext_vector_type(2)));
typedef unsigned int   u32x4 __attribute__((ext_vector_type(4)));

__device__ __forceinline__ unsigned int umax2(unsigned int a, unsigned int b) {
    u16x2 x = __builtin_bit_cast(u16x2, a), y = __builtin_bit_cast(u16x2, b);
#if defined(__has_builtin) && __has_builtin(__builtin_elementwise_max)
    return __builtin_bit_cast(unsigned int, __builtin_elementwise_max(x, y));  // v_pk_max_u16
#else
    u16x2 r; r.x = x.x > y.x ? x.x : y.x; r.y = x.y > y.y ? x.y : y.y;
    return __builtin_bit_cast(unsigned int, r);
#endif
}
__device__ __forceinline__ float frcp(float x) {
#if defined(__has_builtin) && __has_builtin(__builtin_amdgcn_rcpf)
    return __builtin_amdgcn_rcpf(x);
#else
    return 1.0f / x;
#endif
}
__device__ __forceinline__ unsigned short f2bf(float f) {   // RNE, f >= 0 here
    unsigned int u = __builtin_bit_cast(unsigned int, f);
    return (unsigned short)((u + 0x7fffu + ((u >> 16) & 1u)) >> 16);
}
__device__ __forceinline__ float bf2f(unsigned short b) {
    return __builtin_bit_cast(float, (unsigned int)b << 16);
}

// One block (4 waves, 256 threads) per batch row; wave w owns output labels [32w, 32w+32).
// Per step each wave does 8 independent mfma_f32_16x16x32_bf16 (2 N-tiles x 4 K-partials)
// on its own SIMD -> all 4 SIMDs of the CU work in parallel (round-5 lesson: one wave
// gets only 1/4 of CU MFMA throughput). q double-buffered in LDS, one barrier/step.
// Scale: lag-free uniform msc = max(q_{t-1}[0..7]) via one broadcast ds_read (stable,
// validated round 5). Emit is prefetched in 8-step register chunks one chunk ahead so the
// vmcnt(0) drain at __syncthreads (m97) is paid once per 8 steps, not every step.
__global__ __launch_bounds__(256, 1) void k_scan(
        const float* __restrict__ emit, const int* __restrict__ labels,
        const void* __restrict__ masks, const float* __restrict__ T,
        float* __restrict__ out) {
    const int b = blockIdx.x;
    const int tid = threadIdx.x;
    const int w = tid >> 6;                  // wave id 0..3
    const int lane = tid & 63;
    const int g = lane >> 4, m = lane & 15;  // k-group, col
    const int ja = 32 * w + m, jb = ja + 16; // this wave's two output labels (per col m)

    __shared__ __align__(16) short pb[2][L]; // q as bf16 bits, double-buffered
    __shared__ float part[8];                // [0..3] enc partials, [4..7] gold partials
    __shared__ float fsx[4];
    __shared__ int   ib[4];

    // ---- mask encoding self-detect (block-uniform; first 8KB, L2-broadcast) ----
    const unsigned int* mw0 = (const unsigned int*)masks;
    int pred = 0;
    #pragma unroll
    for (int k = 0; k < 8; ++k) {
        unsigned int w0 = mw0[tid + 256 * k];
        pred |= (w0 > 1u && w0 != 0x3f800000u);
    }
    unsigned long long bal = __ballot(pred);
    if (lane == 0) ib[w] = (bal != 0ull) ? 1 : 0;
    __syncthreads();
    const bool isbyte = (ib[0] | ib[1] | ib[2] | ib[3]) != 0;

    // ---- len of row b (prefix-ones mask; per-wave redundant, uniform) ----
    int len;
    {
        int cnt = 0;
        if (isbyte) {
            const unsigned int* mw = (const unsigned int*)masks + b * (S_LEN / 4);
            #pragma unroll
            for (int k = 0; k < 2; ++k) {
                unsigned int w0 = mw[lane + 64 * k];
                cnt += ((w0 & 0xffu) != 0) + ((w0 & 0xff00u) != 0) +
                       ((w0 & 0xff0000u) != 0) + ((w0 & 0xff000000u) != 0);
            }
        } else {
            const unsigned int* mw = (const unsigned int*)masks + b * S_LEN;
            #pragma unroll
            for (int k = 0; k < 8; ++k) cnt += (mw[lane + 64 * k] != 0u);
        }
        #pragma unroll
        for (int off = 32; off; off >>= 1) cnt += __shfl_xor(cnt, off, 64);
        len = cnt;
    }

    // ---- B frags for this wave's two N-tiles (k = kt*32 + g*8 + rr, n = nt*16 + m;
    //      same k-mapping as the A reads below -> permutation cancels) ----
    auto ldb = [&](int nt, int kt) -> short8 {
        short8 r;
        #pragma unroll
        for (int rr = 0; rr < 8; ++rr)
            r[rr] = (short)f2bf(__expf(T[(kt * 32 + g * 8 + rr) * L + nt * 16 + m]));
        return r;
    };
    short8 Ba0 = ldb(2*w, 0), Ba1 = ldb(2*w, 1), Ba2 = ldb(2*w, 2), Ba3 = ldb(2*w, 3);
    short8 Bb0 = ldb(2*w+1, 0), Bb1 = ldb(2*w+1, 1), Bb2 = ldb(2*w+1, 2), Bb3 = ldb(2*w+1, 3);

    float eTpa = __expf(T[ja * L + PAD_ID]);
    float eTpb = __expf(T[jb * L + PAD_ID]);

    // ---- fs0, exact block max -> S, q0 ----
    float fa  = emit[b * L + ja] + T[START_ID * L + ja];
    float fbv = emit[b * L + jb] + T[START_ID * L + jb];
    float mx = fmaxf(fa, fbv);
    #pragma unroll
    for (int off = 32; off; off >>= 1) mx = fmaxf(mx, __shfl_xor(mx, off, 64));
    if (lane == 0) fsx[w] = mx;
    __syncthreads();
    float S = fmaxf(fmaxf(fsx[0], fsx[1]), fmaxf(fsx[2], fsx[3]));
    if (g == 0) {
        pb[0][ja] = (short)f2bf(__expf(fa - S));
        pb[0][jb] = (short)f2bf(__expf(fbv - S));
    }
    __syncthreads();

    // ---- emit prefetch: 8-step register chunks, one chunk ahead ----
    float cura[8], curb[8], nxta[8], nxtb[8];
    #pragma unroll
    for (int k = 0; k < 8; ++k) {
        int tt = 1 + k;
        cura[k] = (tt < len) ? emit[(tt * BATCH + b) * L + ja] : 0.f;
        curb[k] = (tt < len) ? emit[(tt * BATCH + b) * L + jb] : 0.f;
    }

    const f32x4 z = {0.f, 0.f, 0.f, 0.f};

    for (int base = 1; base < len; base += 8) {
        #pragma unroll
        for (int k = 0; k < 8; ++k) {           // next chunk: in flight across this chunk
            int tt = base + 8 + k;
            nxta[k] = (tt < len) ? emit[(tt * BATCH + b) * L + ja] : 0.f;
            nxtb[k] = (tt < len) ? emit[(tt * BATCH + b) * L + jb] : 0.f;
        }
        #pragma unroll
        for (int k = 0; k < 8; ++k) {
            int t = base + k;
            if (t >= len) break;                // uniform across block
            const short8* l8 = (const short8*)pb[(t - 1) & 1];
            short8 A0 = l8[0 + g], A1 = l8[4 + g], A2 = l8[8 + g], A3 = l8[12 + g];
            short8 M8 = l8[0];                  // uniform broadcast: q_{t-1}[0..7]

            u32x4 mu = __builtin_bit_cast(u32x4, M8);
            unsigned int um = umax2(umax2(mu.x, mu.y), umax2(mu.z, mu.w));
            u16x2 uh = __builtin_bit_cast(u16x2, um);
            float msc = bf2f(uh.x > uh.y ? uh.x : uh.y);
            float kk = frcp(msc);

            // 8 independent MFMAs (no accumulate chains)
            f32x4 ca0 = __builtin_amdgcn_mfma_f32_16x16x32_bf16(A0, Ba0, z, 0, 0, 0);
            f32x4 ca1 = __builtin_amdgcn_mfma_f32_16x16x32_bf16(A1, Ba1, z, 0, 0, 0);
            f32x4 ca2 = __builtin_amdgcn_mfma_f32_16x16x32_bf16(A2, Ba2, z, 0, 0, 0);
            f32x4 ca3 = __builtin_amdgcn_mfma_f32_16x16x32_bf16(A3, Ba3, z, 0, 0, 0);
            f32x4 cb0 = __builtin_amdgcn_mfma_f32_16x16x32_bf16(A0, Bb0, z, 0, 0, 0);
            f32x4 cb1 = __builtin_amdgcn_mfma_f32_16x16x32_bf16(A1, Bb1, z, 0, 0, 0);
            f32x4 cb2 = __builtin_amdgcn_mfma_f32_16x16x32_bf16(A2, Bb2, z, 0, 0, 0);
            f32x4 cb3 = __builtin_amdgcn_mfma_f32_16x16x32_bf16(A3, Bb3, z, 0, 0, 0);
            float ca = (ca0[0] + ca1[0]) + (ca2[0] + ca3[0]);  // rows replicated: [0] = col m
            float cb = (cb0[0] + cb1[0]) + (cb2[0] + cb3[0]);

            float pa = ca * kk * __expf(cura[k]);
            float pv = cb * kk * __expf(curb[k]);
            if (g == 0) {
                pb[t & 1][ja] = (short)f2bf(pa);
                pb[t & 1][jb] = (short)f2bf(pv);
            }
            S += __logf(msc);
            __syncthreads();
        }
        #pragma unroll
        for (int k = 0; k < 8; ++k) { cura[k] = nxta[k]; curb[k] = nxtb[k]; }
    }

    // ---- encode_b = S + log(sum_j q_j * exp(T[j][PAD])) ----
    const int fbuf = (len - 1) & 1;
    float ev = 0.f;
    if (g == 0)
        ev = bf2f((unsigned short)pb[fbuf][ja]) * eTpa
           + bf2f((unsigned short)pb[fbuf][jb]) * eTpb;
    #pragma unroll
    for (int off = 32; off; off >>= 1) ev += __shfl_xor(ev, off, 64);
    if (lane == 0) part[w] = ev;

    // ---- gold_b over all 256 threads ----
    float gsum = 0.f;
    for (int t = tid; t < len; t += 256) {
        int nxt = labels[b * S_LEN + t];
        int prv = t ? labels[b * S_LEN + t - 1] : START_ID;
        gsum += emit[(t * BATCH + b) * L + nxt] + T[prv * L + nxt];
        if (t == len - 1) gsum += T[nxt * L + PAD_ID];
    }
    #pragma unroll
    for (int off = 32; off; off >>= 1) gsum += __shfl_xor(gsum, off, 64);
    if (lane == 0) part[4 + w] = gsum;
    __syncthreads();

    if (tid == 0) {
        float enc  = S + __logf((part[0] + part[1]) + (part[2] + part[3]));
        float gold = (part[4] + part[5]) + (part[6] + part[7]);
        atomicAdd(out, enc - gold);
    }
}

extern "C" void kernel_launch(void* const* d_in, const int* in_sizes, int n_in,
                              void* d_out, int out_size, void* d_ws, size_t ws_size,
                              hipStream_t stream) {
    const float* emit   = (const float*)d_in[0];
    const int*   labels = (const int*)d_in[1];
    const void*  masks  = d_in[2];
    const float* T      = (const float*)d_in[3];
    float* out = (float*)d_out;

    hipMemsetAsync(d_out, 0, sizeof(float), stream);
    k_scan<<<dim3(BATCH), dim3(256), 0, stream>>>(emit, labels, masks, T, out);
}